// Round 1
// baseline (1561.417 us; speedup 1.0000x reference)
//
#include <hip/hip_runtime.h>
#include <math.h>

#define MDIM 128
#define MY 10
#define GAMMA 0.8f
#define KITER 5

// ---------------------------------------------------------------- transpose
// X [128][n] row-major  ->  Y0 [n][128] row-major
__global__ void k_transpose(const float* __restrict__ X, float* __restrict__ Y0, int n) {
    __shared__ float tile[32][33];
    int r0 = blockIdx.x * 32;
    int f0 = blockIdx.y * 32;
    int tx = threadIdx.x, ty = threadIdx.y;  // 32 x 8
    #pragma unroll
    for (int i = 0; i < 32; i += 8) {
        tile[ty + i][tx] = X[(size_t)(f0 + ty + i) * n + (r0 + tx)];
    }
    __syncthreads();
    #pragma unroll
    for (int i = 0; i < 32; i += 8) {
        Y0[(size_t)(r0 + ty + i) * MDIM + (f0 + tx)] = tile[tx][ty + i];
    }
}

// ---------------------------------------------------------------- Gram matrix
// FF = F^T F  (exactly symmetric), accumulate ||FF||_F^2 into normAcc
__global__ void k_gram(const float* __restrict__ F, float* __restrict__ FF,
                       float* __restrict__ normAcc) {
    int i = blockIdx.x, j = threadIdx.x;
    float acc = 0.f;
    for (int k = 0; k < MDIM; ++k)
        acc = fmaf(F[k * MDIM + i], F[k * MDIM + j], acc);
    FF[i * MDIM + j] = acc;
    __shared__ float red[MDIM];
    red[j] = acc * acc;
    __syncthreads();
    for (int s = 64; s > 0; s >>= 1) {
        if (j < s) red[j] += red[j + s];
        __syncthreads();
    }
    if (j == 0) atomicAdd(normAcc, red[0]);
}

// G = gamma * FF / (||FF||_F + 1e-6)   (gamma folded in here)
__global__ void k_gnorm(const float* __restrict__ FF, const float* __restrict__ normAcc,
                        float* __restrict__ G) {
    int idx = blockIdx.x * 256 + threadIdx.x;
    float s = GAMMA / (sqrtf(*normAcc) + 1e-6f);
    G[idx] = FF[idx] * s;
}

// ---------------------------------------------------------------- CSR build
__global__ void k_hist(const int* __restrict__ erow, int* __restrict__ cnt, int E) {
    int e = blockIdx.x * 256 + threadIdx.x;
    if (e < E) atomicAdd(&cnt[erow[e]], 1);
}

__global__ void k_scan(const int* __restrict__ cnt, int* __restrict__ row_off, int n) {
    __shared__ int s[1024];
    int tid = threadIdx.x;
    int chunk = (n + 1023) / 1024;
    int base = tid * chunk;
    int sum = 0;
    for (int i = 0; i < chunk; ++i) {
        int idx = base + i;
        if (idx < n) sum += cnt[idx];
    }
    s[tid] = sum;
    __syncthreads();
    for (int off = 1; off < 1024; off <<= 1) {
        int v = (tid >= off) ? s[tid - off] : 0;
        __syncthreads();
        s[tid] += v;
        __syncthreads();
    }
    int run = s[tid] - sum;  // exclusive prefix
    for (int i = 0; i < chunk; ++i) {
        int idx = base + i;
        if (idx < n) { row_off[idx] = run; run += cnt[idx]; }
    }
    if (tid == 1023) row_off[n] = s[1023];
}

__global__ void k_scatter(const int* __restrict__ erow, const int* __restrict__ ecol,
                          const float* __restrict__ eval_, int* __restrict__ cursor,
                          int* __restrict__ csr_col, float* __restrict__ csr_val, int E) {
    int e = blockIdx.x * 256 + threadIdx.x;
    if (e < E) {
        int r = erow[e];
        int pos = atomicAdd(&cursor[r], 1);
        csr_col[pos] = ecol[e];
        csr_val[pos] = eval_[e];
    }
}

// ---------------------------------------------------------------- SpMM: SY = S @ Yin
// 8 rows per block of 256; 32 lanes x float4 = one 512B row per edge
__global__ void __launch_bounds__(256) k_spmm(const float* __restrict__ Yin,
                                              const int* __restrict__ row_off,
                                              const int* __restrict__ csr_col,
                                              const float* __restrict__ csr_val,
                                              float* __restrict__ SY, int n) {
    int row = blockIdx.x * 8 + (threadIdx.x >> 5);
    int tx = threadIdx.x & 31;
    if (row >= n) return;
    int e0 = row_off[row], e1 = row_off[row + 1];
    float4 acc = make_float4(0.f, 0.f, 0.f, 0.f);
    for (int e = e0; e < e1; ++e) {
        float v = csr_val[e];
        int c = csr_col[e];
        const float4 yv = *(const float4*)&Yin[(size_t)c * MDIM + tx * 4];
        acc.x = fmaf(v, yv.x, acc.x);
        acc.y = fmaf(v, yv.y, acc.y);
        acc.z = fmaf(v, yv.z, acc.z);
        acc.w = fmaf(v, yv.w, acc.w);
    }
    *(float4*)&SY[(size_t)row * MDIM + tx * 4] = acc;
}

// ---------------------------------------------------------------- dense update
// Yout = SY @ G + Y0   (gamma pre-folded into G; G symmetric so this is G^T too)
// block 256 = 32 lanes(4 feats) x 8 groups(4 rows); 32 rows/block; G in LDS (64KB)
__global__ void __launch_bounds__(256) k_gemm(const float* __restrict__ SY,
                                              const float* __restrict__ G,
                                              const float* __restrict__ Y0,
                                              float* __restrict__ Yout, int n) {
    __shared__ float sG[MDIM * MDIM];
    int tid = threadIdx.x;
    #pragma unroll
    for (int i = 0; i < 16; ++i) {
        int idx = (i * 256 + tid) * 4;
        *(float4*)&sG[idx] = *(const float4*)&G[idx];
    }
    __syncthreads();
    int tx = tid & 31, ty = tid >> 5;
    size_t r0 = (size_t)blockIdx.x * 32 + ty * 4;
    int f0 = tx * 4;
    float4 acc[4];
    #pragma unroll
    for (int i = 0; i < 4; ++i) acc[i] = make_float4(0.f, 0.f, 0.f, 0.f);
    for (int j = 0; j < MDIM; j += 4) {
        float4 g0 = *(const float4*)&sG[(j + 0) * MDIM + f0];
        float4 g1 = *(const float4*)&sG[(j + 1) * MDIM + f0];
        float4 g2 = *(const float4*)&sG[(j + 2) * MDIM + f0];
        float4 g3 = *(const float4*)&sG[(j + 3) * MDIM + f0];
        #pragma unroll
        for (int i = 0; i < 4; ++i) {
            float4 sr = *(const float4*)&SY[(r0 + i) * MDIM + j];
            acc[i].x = fmaf(sr.x, g0.x, acc[i].x);
            acc[i].y = fmaf(sr.x, g0.y, acc[i].y);
            acc[i].z = fmaf(sr.x, g0.z, acc[i].z);
            acc[i].w = fmaf(sr.x, g0.w, acc[i].w);
            acc[i].x = fmaf(sr.y, g1.x, acc[i].x);
            acc[i].y = fmaf(sr.y, g1.y, acc[i].y);
            acc[i].z = fmaf(sr.y, g1.z, acc[i].z);
            acc[i].w = fmaf(sr.y, g1.w, acc[i].w);
            acc[i].x = fmaf(sr.z, g2.x, acc[i].x);
            acc[i].y = fmaf(sr.z, g2.y, acc[i].y);
            acc[i].z = fmaf(sr.z, g2.z, acc[i].z);
            acc[i].w = fmaf(sr.z, g2.w, acc[i].w);
            acc[i].x = fmaf(sr.w, g3.x, acc[i].x);
            acc[i].y = fmaf(sr.w, g3.y, acc[i].y);
            acc[i].z = fmaf(sr.w, g3.z, acc[i].z);
            acc[i].w = fmaf(sr.w, g3.w, acc[i].w);
        }
    }
    #pragma unroll
    for (int i = 0; i < 4; ++i) {
        float4 y0 = *(const float4*)&Y0[(r0 + i) * MDIM + f0];
        float4 o;
        o.x = acc[i].x + y0.x;
        o.y = acc[i].y + y0.y;
        o.z = acc[i].z + y0.z;
        o.w = acc[i].w + y0.w;
        *(float4*)&Yout[(r0 + i) * MDIM + f0] = o;
    }
}

// ---------------------------------------------------------------- BN stats
__global__ void k_bnstats(const float* __restrict__ Y, float* __restrict__ stats, int n) {
    int f = threadIdx.x;
    int chunk = (n + gridDim.x - 1) / gridDim.x;
    int rbeg = blockIdx.x * chunk;
    int rend = rbeg + chunk;
    if (rend > n) rend = n;
    float s = 0.f, sq = 0.f;
    for (int r = rbeg; r < rend; ++r) {
        float v = Y[(size_t)r * MDIM + f];
        s += v;
        sq = fmaf(v, v, sq);
    }
    atomicAdd(&stats[f], s);
    atomicAdd(&stats[MDIM + f], sq);
}

// fold BN into projection: Bs[o][f] = B[o][f]*rs*w;  c[o] = sum_f (b - mu*rs*w)*B[o][f]
__global__ void k_finalize(const float* __restrict__ stats, const float* __restrict__ B,
                           const float* __restrict__ bnw, const float* __restrict__ bnb,
                           float* __restrict__ Bs, float* __restrict__ cvec, int n) {
    int f = threadIdx.x;
    float inv_n = 1.f / (float)n;
    float mu = stats[f] * inv_n;
    float var = stats[MDIM + f] * inv_n - mu * mu;
    float rs = rsqrtf(var + 1e-5f);
    float sw = rs * bnw[f];
    float cv = bnb[f] - mu * sw;
    __shared__ float red[MDIM];
    for (int o = 0; o < MY; ++o) {
        float b = B[o * MDIM + f];
        Bs[o * MDIM + f] = b * sw;
        red[f] = b * cv;
        __syncthreads();
        for (int s = 64; s > 0; s >>= 1) {
            if (f < s) red[f] += red[f + s];
            __syncthreads();
        }
        if (f == 0) cvec[o] = red[0];
        __syncthreads();
    }
}

// ---------------------------------------------------------------- projection
// out[r][o] = Y[r][:] . Bs[o][:] + c[o];  16 rows per block
__global__ void __launch_bounds__(256) k_project(const float* __restrict__ Y,
                                                 const float* __restrict__ Bs,
                                                 const float* __restrict__ cvec,
                                                 float* __restrict__ out, int n) {
    __shared__ float yt[16 * 129];
    __shared__ float sB[MY * 129];
    __shared__ float sc[MY];
    int tid = threadIdx.x;
    size_t rbase = (size_t)blockIdx.x * 16;
    for (int idx = tid; idx < 16 * MDIM; idx += 256) {
        int r = idx >> 7, f = idx & 127;
        yt[r * 129 + f] = Y[(rbase + r) * MDIM + f];
    }
    for (int idx = tid; idx < MY * MDIM; idx += 256) {
        int o = idx >> 7, f = idx & 127;
        sB[o * 129 + f] = Bs[idx];
    }
    if (tid < MY) sc[tid] = cvec[tid];
    __syncthreads();
    if (tid < 16 * MY) {
        int r = tid / MY, o = tid % MY;
        float acc = sc[o];
        for (int f = 0; f < MDIM; ++f)
            acc = fmaf(yt[r * 129 + f], sB[o * 129 + f], acc);
        out[(rbase + r) * MY + o] = acc;
    }
}

// ---------------------------------------------------------------- launch
extern "C" void kernel_launch(void* const* d_in, const int* in_sizes, int n_in,
                              void* d_out, int out_size, void* d_ws, size_t ws_size,
                              hipStream_t stream) {
    const float* X    = (const float*)d_in[0];  // [128][n]
    const float* F    = (const float*)d_in[1];  // [128][128]
    const float* B    = (const float*)d_in[2];  // [10][128]
    const float* bnw  = (const float*)d_in[3];
    const float* bnb  = (const float*)d_in[4];
    const float* ev   = (const float*)d_in[5];  // [E]
    const int*   erow = (const int*)d_in[6];
    const int*   ecol = (const int*)d_in[7];
    float* out = (float*)d_out;
    const int n = in_sizes[0] / MDIM;  // 100000
    const int E = in_sizes[5];         // 1600000

    char* w = (char*)d_ws;
    size_t off = 0;
    auto carve = [&](size_t bytes) -> void* {
        void* p = w + off;
        off += (bytes + 255) & ~(size_t)255;
        return p;
    };
    float* Y0      = (float*)carve((size_t)n * MDIM * 4);  // 51.2 MB
    float* Ycur    = (float*)carve((size_t)n * MDIM * 4);  // 51.2 MB
    float* SY      = (float*)carve((size_t)n * MDIM * 4);  // 51.2 MB
    float* FF      = (float*)carve(MDIM * MDIM * 4);
    float* G       = (float*)carve(MDIM * MDIM * 4);
    float* csr_val = (float*)carve((size_t)E * 4);
    int*   csr_col = (int*)carve((size_t)E * 4);
    int*   row_off = (int*)carve((size_t)(n + 1) * 4);
    int*   cursor  = (int*)carve((size_t)n * 4);
    int*   cnt     = (int*)carve((size_t)n * 4);
    float* normAcc = (float*)carve(4);
    float* stats   = (float*)carve(2 * MDIM * 4);
    float* Bs      = (float*)carve(MY * MDIM * 4);
    float* cvec    = (float*)carve(MY * 4);
    (void)ws_size;

    hipMemsetAsync(cnt, 0, (size_t)n * 4, stream);
    hipMemsetAsync(normAcc, 0, 4, stream);
    hipMemsetAsync(stats, 0, 2 * MDIM * 4, stream);

    k_transpose<<<dim3(n / 32, MDIM / 32), dim3(32, 8), 0, stream>>>(X, Y0, n);
    k_gram<<<MDIM, MDIM, 0, stream>>>(F, FF, normAcc);
    k_gnorm<<<MDIM * MDIM / 256, 256, 0, stream>>>(FF, normAcc, G);

    k_hist<<<(E + 255) / 256, 256, 0, stream>>>(erow, cnt, E);
    k_scan<<<1, 1024, 0, stream>>>(cnt, row_off, n);
    hipMemcpyAsync(cursor, row_off, (size_t)n * 4, hipMemcpyDeviceToDevice, stream);
    k_scatter<<<(E + 255) / 256, 256, 0, stream>>>(erow, ecol, ev, cursor, csr_col, csr_val, E);

    const float* Yin = Y0;
    for (int k = 0; k < KITER; ++k) {
        k_spmm<<<(n + 7) / 8, 256, 0, stream>>>(Yin, row_off, csr_col, csr_val, SY, n);
        k_gemm<<<n / 32, 256, 0, stream>>>(SY, G, Y0, Ycur, n);
        Yin = Ycur;
    }

    k_bnstats<<<256, MDIM, 0, stream>>>(Ycur, stats, n);
    k_finalize<<<1, MDIM, 0, stream>>>(stats, B, bnw, bnb, Bs, cvec, n);
    k_project<<<n / 16, 256, 0, stream>>>(Ycur, Bs, cvec, out, n);
}

// Round 2
// 1355.030 us; speedup vs baseline: 1.1523x; 1.1523x over previous
//
#include <hip/hip_runtime.h>
#include <math.h>

#define MDIM 128
#define MY 10
#define GAMMA 0.8f
#define KITER 5

// ---------------------------------------------------------------- transpose
// X [128][n] row-major  ->  Y0 [n][128] row-major
__global__ void k_transpose(const float* __restrict__ X, float* __restrict__ Y0, int n) {
    __shared__ float tile[32][33];
    int r0 = blockIdx.x * 32;
    int f0 = blockIdx.y * 32;
    int tx = threadIdx.x, ty = threadIdx.y;  // 32 x 8
    #pragma unroll
    for (int i = 0; i < 32; i += 8) {
        tile[ty + i][tx] = X[(size_t)(f0 + ty + i) * n + (r0 + tx)];
    }
    __syncthreads();
    #pragma unroll
    for (int i = 0; i < 32; i += 8) {
        Y0[(size_t)(r0 + ty + i) * MDIM + (f0 + tx)] = tile[tx][ty + i];
    }
}

// ---------------------------------------------------------------- Gram matrix
__global__ void k_gram(const float* __restrict__ F, float* __restrict__ FF,
                       float* __restrict__ normAcc) {
    int i = blockIdx.x, j = threadIdx.x;
    float acc = 0.f;
    for (int k = 0; k < MDIM; ++k)
        acc = fmaf(F[k * MDIM + i], F[k * MDIM + j], acc);
    FF[i * MDIM + j] = acc;
    __shared__ float red[MDIM];
    red[j] = acc * acc;
    __syncthreads();
    for (int s = 64; s > 0; s >>= 1) {
        if (j < s) red[j] += red[j + s];
        __syncthreads();
    }
    if (j == 0) atomicAdd(normAcc, red[0]);
}

__global__ void k_gnorm(const float* __restrict__ FF, const float* __restrict__ normAcc,
                        float* __restrict__ G) {
    int idx = blockIdx.x * 256 + threadIdx.x;
    float s = GAMMA / (sqrtf(*normAcc) + 1e-6f);
    G[idx] = FF[idx] * s;
}

// ---------------------------------------------------------------- CSR build
__global__ void k_hist(const int* __restrict__ erow, int* __restrict__ cnt, int E) {
    int e = blockIdx.x * 256 + threadIdx.x;
    if (e < E) atomicAdd(&cnt[erow[e]], 1);
}

// 3-phase multi-block exclusive scan of cnt[n] -> row_off[n+1]
// phase 1: per-block (1024 elems) sums
__global__ void k_scan1(const int* __restrict__ cnt, int* __restrict__ blockSums, int n) {
    int tid = threadIdx.x;  // 256
    int base = blockIdx.x * 1024 + tid * 4;
    int s = 0;
    if (base + 3 < n) {
        int4 v = *(const int4*)&cnt[base];
        s = v.x + v.y + v.z + v.w;
    } else {
        for (int i = 0; i < 4; ++i)
            if (base + i < n) s += cnt[base + i];
    }
    __shared__ int red[256];
    red[tid] = s;
    __syncthreads();
    for (int st = 128; st > 0; st >>= 1) {
        if (tid < st) red[tid] += red[tid + st];
        __syncthreads();
    }
    if (tid == 0) blockSums[blockIdx.x] = red[0];
}

// phase 2: exclusive scan of block sums (nb <= 256), also writes row_off[n] = total
__global__ void k_scan2(int* __restrict__ blockSums, int* __restrict__ row_off,
                        int nb, int n) {
    __shared__ int s[256];
    int tid = threadIdx.x;  // 256
    int v = (tid < nb) ? blockSums[tid] : 0;
    s[tid] = v;
    __syncthreads();
    for (int off = 1; off < 256; off <<= 1) {
        int t = (tid >= off) ? s[tid - off] : 0;
        __syncthreads();
        s[tid] += t;
        __syncthreads();
    }
    if (tid < nb) blockSums[tid] = s[tid] - v;  // exclusive
    if (tid == 0) row_off[n] = s[255];          // grand total
}

// phase 3: local exclusive scan + block offset
__global__ void k_scan3(const int* __restrict__ cnt, const int* __restrict__ blockOff,
                        int* __restrict__ row_off, int n) {
    int tid = threadIdx.x;  // 256
    int base = blockIdx.x * 1024 + tid * 4;
    int v[4];
    #pragma unroll
    for (int i = 0; i < 4; ++i) v[i] = (base + i < n) ? cnt[base + i] : 0;
    int local = v[0] + v[1] + v[2] + v[3];
    __shared__ int s[256];
    s[tid] = local;
    __syncthreads();
    for (int off = 1; off < 256; off <<= 1) {
        int t = (tid >= off) ? s[tid - off] : 0;
        __syncthreads();
        s[tid] += t;
        __syncthreads();
    }
    int excl = s[tid] - local + blockOff[blockIdx.x];
    #pragma unroll
    for (int i = 0; i < 4; ++i) {
        if (base + i < n) { row_off[base + i] = excl; excl += v[i]; }
    }
}

__global__ void k_scatter(const int* __restrict__ erow, const int* __restrict__ ecol,
                          const float* __restrict__ eval_, int* __restrict__ cursor,
                          int* __restrict__ csr_col, float* __restrict__ csr_val, int E) {
    int e = blockIdx.x * 256 + threadIdx.x;
    if (e < E) {
        int r = erow[e];
        int pos = atomicAdd(&cursor[r], 1);
        csr_col[pos] = ecol[e];
        csr_val[pos] = eval_[e];
    }
}

// ---------------------------------------------------------------- SpMM: SY = S @ Yin
// 8 rows per block of 256; 32 lanes x float4 = one 512B row per edge.
// Edge loop unrolled x4: 4 independent gathers in flight per half-wave (MLP).
__global__ void __launch_bounds__(256) k_spmm(const float* __restrict__ Yin,
                                              const int* __restrict__ row_off,
                                              const int* __restrict__ csr_col,
                                              const float* __restrict__ csr_val,
                                              float* __restrict__ SY, int n) {
    int row = blockIdx.x * 8 + (threadIdx.x >> 5);
    int tx = threadIdx.x & 31;
    if (row >= n) return;
    int e0 = row_off[row], e1 = row_off[row + 1];
    float4 acc = make_float4(0.f, 0.f, 0.f, 0.f);
    int e = e0;
    for (; e + 4 <= e1; e += 4) {
        float v0 = csr_val[e + 0];
        float v1 = csr_val[e + 1];
        float v2 = csr_val[e + 2];
        float v3 = csr_val[e + 3];
        int c0 = csr_col[e + 0];
        int c1 = csr_col[e + 1];
        int c2 = csr_col[e + 2];
        int c3 = csr_col[e + 3];
        const float4 y0 = *(const float4*)&Yin[(size_t)c0 * MDIM + tx * 4];
        const float4 y1 = *(const float4*)&Yin[(size_t)c1 * MDIM + tx * 4];
        const float4 y2 = *(const float4*)&Yin[(size_t)c2 * MDIM + tx * 4];
        const float4 y3 = *(const float4*)&Yin[(size_t)c3 * MDIM + tx * 4];
        acc.x = fmaf(v0, y0.x, acc.x);
        acc.y = fmaf(v0, y0.y, acc.y);
        acc.z = fmaf(v0, y0.z, acc.z);
        acc.w = fmaf(v0, y0.w, acc.w);
        acc.x = fmaf(v1, y1.x, acc.x);
        acc.y = fmaf(v1, y1.y, acc.y);
        acc.z = fmaf(v1, y1.z, acc.z);
        acc.w = fmaf(v1, y1.w, acc.w);
        acc.x = fmaf(v2, y2.x, acc.x);
        acc.y = fmaf(v2, y2.y, acc.y);
        acc.z = fmaf(v2, y2.z, acc.z);
        acc.w = fmaf(v2, y2.w, acc.w);
        acc.x = fmaf(v3, y3.x, acc.x);
        acc.y = fmaf(v3, y3.y, acc.y);
        acc.z = fmaf(v3, y3.z, acc.z);
        acc.w = fmaf(v3, y3.w, acc.w);
    }
    for (; e < e1; ++e) {
        float v = csr_val[e];
        int c = csr_col[e];
        const float4 yv = *(const float4*)&Yin[(size_t)c * MDIM + tx * 4];
        acc.x = fmaf(v, yv.x, acc.x);
        acc.y = fmaf(v, yv.y, acc.y);
        acc.z = fmaf(v, yv.z, acc.z);
        acc.w = fmaf(v, yv.w, acc.w);
    }
    *(float4*)&SY[(size_t)row * MDIM + tx * 4] = acc;
}

// ---------------------------------------------------------------- dense update
// Yout = SY @ G + Y0   (gamma pre-folded into G; G symmetric)
__global__ void __launch_bounds__(256) k_gemm(const float* __restrict__ SY,
                                              const float* __restrict__ G,
                                              const float* __restrict__ Y0,
                                              float* __restrict__ Yout, int n) {
    __shared__ float sG[MDIM * MDIM];
    int tid = threadIdx.x;
    #pragma unroll
    for (int i = 0; i < 16; ++i) {
        int idx = (i * 256 + tid) * 4;
        *(float4*)&sG[idx] = *(const float4*)&G[idx];
    }
    __syncthreads();
    int tx = tid & 31, ty = tid >> 5;
    size_t r0 = (size_t)blockIdx.x * 32 + ty * 4;
    int f0 = tx * 4;
    float4 acc[4];
    #pragma unroll
    for (int i = 0; i < 4; ++i) acc[i] = make_float4(0.f, 0.f, 0.f, 0.f);
    for (int j = 0; j < MDIM; j += 4) {
        float4 g0 = *(const float4*)&sG[(j + 0) * MDIM + f0];
        float4 g1 = *(const float4*)&sG[(j + 1) * MDIM + f0];
        float4 g2 = *(const float4*)&sG[(j + 2) * MDIM + f0];
        float4 g3 = *(const float4*)&sG[(j + 3) * MDIM + f0];
        #pragma unroll
        for (int i = 0; i < 4; ++i) {
            float4 sr = *(const float4*)&SY[(r0 + i) * MDIM + j];
            acc[i].x = fmaf(sr.x, g0.x, acc[i].x);
            acc[i].y = fmaf(sr.x, g0.y, acc[i].y);
            acc[i].z = fmaf(sr.x, g0.z, acc[i].z);
            acc[i].w = fmaf(sr.x, g0.w, acc[i].w);
            acc[i].x = fmaf(sr.y, g1.x, acc[i].x);
            acc[i].y = fmaf(sr.y, g1.y, acc[i].y);
            acc[i].z = fmaf(sr.y, g1.z, acc[i].z);
            acc[i].w = fmaf(sr.y, g1.w, acc[i].w);
            acc[i].x = fmaf(sr.z, g2.x, acc[i].x);
            acc[i].y = fmaf(sr.z, g2.y, acc[i].y);
            acc[i].z = fmaf(sr.z, g2.z, acc[i].z);
            acc[i].w = fmaf(sr.z, g2.w, acc[i].w);
            acc[i].x = fmaf(sr.w, g3.x, acc[i].x);
            acc[i].y = fmaf(sr.w, g3.y, acc[i].y);
            acc[i].z = fmaf(sr.w, g3.z, acc[i].z);
            acc[i].w = fmaf(sr.w, g3.w, acc[i].w);
        }
    }
    #pragma unroll
    for (int i = 0; i < 4; ++i) {
        float4 y0 = *(const float4*)&Y0[(r0 + i) * MDIM + f0];
        float4 o;
        o.x = acc[i].x + y0.x;
        o.y = acc[i].y + y0.y;
        o.z = acc[i].z + y0.z;
        o.w = acc[i].w + y0.w;
        *(float4*)&Yout[(r0 + i) * MDIM + f0] = o;
    }
}

// ---------------------------------------------------------------- BN stats
__global__ void k_bnstats(const float* __restrict__ Y, float* __restrict__ stats, int n) {
    int f = threadIdx.x;
    int chunk = (n + gridDim.x - 1) / gridDim.x;
    int rbeg = blockIdx.x * chunk;
    int rend = rbeg + chunk;
    if (rend > n) rend = n;
    float s = 0.f, sq = 0.f;
    for (int r = rbeg; r < rend; ++r) {
        float v = Y[(size_t)r * MDIM + f];
        s += v;
        sq = fmaf(v, v, sq);
    }
    atomicAdd(&stats[f], s);
    atomicAdd(&stats[MDIM + f], sq);
}

__global__ void k_finalize(const float* __restrict__ stats, const float* __restrict__ B,
                           const float* __restrict__ bnw, const float* __restrict__ bnb,
                           float* __restrict__ Bs, float* __restrict__ cvec, int n) {
    int f = threadIdx.x;
    float inv_n = 1.f / (float)n;
    float mu = stats[f] * inv_n;
    float var = stats[MDIM + f] * inv_n - mu * mu;
    float rs = rsqrtf(var + 1e-5f);
    float sw = rs * bnw[f];
    float cv = bnb[f] - mu * sw;
    __shared__ float red[MDIM];
    for (int o = 0; o < MY; ++o) {
        float b = B[o * MDIM + f];
        Bs[o * MDIM + f] = b * sw;
        red[f] = b * cv;
        __syncthreads();
        for (int s = 64; s > 0; s >>= 1) {
            if (f < s) red[f] += red[f + s];
            __syncthreads();
        }
        if (f == 0) cvec[o] = red[0];
        __syncthreads();
    }
}

// ---------------------------------------------------------------- projection
__global__ void __launch_bounds__(256) k_project(const float* __restrict__ Y,
                                                 const float* __restrict__ Bs,
                                                 const float* __restrict__ cvec,
                                                 float* __restrict__ out, int n) {
    __shared__ float yt[16 * 129];
    __shared__ float sB[MY * 129];
    __shared__ float sc[MY];
    int tid = threadIdx.x;
    size_t rbase = (size_t)blockIdx.x * 16;
    for (int idx = tid; idx < 16 * MDIM; idx += 256) {
        int r = idx >> 7, f = idx & 127;
        yt[r * 129 + f] = Y[(rbase + r) * MDIM + f];
    }
    for (int idx = tid; idx < MY * MDIM; idx += 256) {
        int o = idx >> 7, f = idx & 127;
        sB[o * 129 + f] = Bs[idx];
    }
    if (tid < MY) sc[tid] = cvec[tid];
    __syncthreads();
    if (tid < 16 * MY) {
        int r = tid / MY, o = tid % MY;
        float acc = sc[o];
        for (int f = 0; f < MDIM; ++f)
            acc = fmaf(yt[r * 129 + f], sB[o * 129 + f], acc);
        out[(rbase + r) * MY + o] = acc;
    }
}

// ---------------------------------------------------------------- launch
extern "C" void kernel_launch(void* const* d_in, const int* in_sizes, int n_in,
                              void* d_out, int out_size, void* d_ws, size_t ws_size,
                              hipStream_t stream) {
    const float* X    = (const float*)d_in[0];  // [128][n]
    const float* F    = (const float*)d_in[1];  // [128][128]
    const float* B    = (const float*)d_in[2];  // [10][128]
    const float* bnw  = (const float*)d_in[3];
    const float* bnb  = (const float*)d_in[4];
    const float* ev   = (const float*)d_in[5];  // [E]
    const int*   erow = (const int*)d_in[6];
    const int*   ecol = (const int*)d_in[7];
    float* out = (float*)d_out;
    const int n = in_sizes[0] / MDIM;  // 100000
    const int E = in_sizes[5];         // 1600000

    char* w = (char*)d_ws;
    size_t off = 0;
    auto carve = [&](size_t bytes) -> void* {
        void* p = w + off;
        off += (bytes + 255) & ~(size_t)255;
        return p;
    };
    float* Y0        = (float*)carve((size_t)n * MDIM * 4);
    float* Ycur      = (float*)carve((size_t)n * MDIM * 4);
    float* SY        = (float*)carve((size_t)n * MDIM * 4);
    float* FF        = (float*)carve(MDIM * MDIM * 4);
    float* G         = (float*)carve(MDIM * MDIM * 4);
    float* csr_val   = (float*)carve((size_t)E * 4);
    int*   csr_col   = (int*)carve((size_t)E * 4);
    int*   row_off   = (int*)carve((size_t)(n + 1) * 4);
    int*   cursor    = (int*)carve((size_t)n * 4);
    int*   cnt       = (int*)carve((size_t)n * 4);
    int*   blockSums = (int*)carve(1024 * 4);
    float* normAcc   = (float*)carve(4);
    float* stats     = (float*)carve(2 * MDIM * 4);
    float* Bs        = (float*)carve(MY * MDIM * 4);
    float* cvec      = (float*)carve(MY * 4);
    (void)ws_size;

    hipMemsetAsync(cnt, 0, (size_t)n * 4, stream);
    hipMemsetAsync(normAcc, 0, 4, stream);
    hipMemsetAsync(stats, 0, 2 * MDIM * 4, stream);

    k_transpose<<<dim3(n / 32, MDIM / 32), dim3(32, 8), 0, stream>>>(X, Y0, n);
    k_gram<<<MDIM, MDIM, 0, stream>>>(F, FF, normAcc);
    k_gnorm<<<MDIM * MDIM / 256, 256, 0, stream>>>(FF, normAcc, G);

    const int nb = (n + 1023) / 1024;  // 98
    k_hist<<<(E + 255) / 256, 256, 0, stream>>>(erow, cnt, E);
    k_scan1<<<nb, 256, 0, stream>>>(cnt, blockSums, n);
    k_scan2<<<1, 256, 0, stream>>>(blockSums, row_off, nb, n);
    k_scan3<<<nb, 256, 0, stream>>>(cnt, blockSums, row_off, n);
    hipMemcpyAsync(cursor, row_off, (size_t)n * 4, hipMemcpyDeviceToDevice, stream);
    k_scatter<<<(E + 255) / 256, 256, 0, stream>>>(erow, ecol, ev, cursor, csr_col, csr_val, E);

    const float* Yin = Y0;
    for (int k = 0; k < KITER; ++k) {
        k_spmm<<<(n + 7) / 8, 256, 0, stream>>>(Yin, row_off, csr_col, csr_val, SY, n);
        k_gemm<<<n / 32, 256, 0, stream>>>(SY, G, Y0, Ycur, n);
        Yin = Ycur;
    }

    k_bnstats<<<256, MDIM, 0, stream>>>(Ycur, stats, n);
    k_finalize<<<1, MDIM, 0, stream>>>(stats, B, bnw, bnb, Bs, cvec, n);
    k_project<<<n / 16, 256, 0, stream>>>(Ycur, Bs, cvec, out, n);
}

// Round 3
// 1117.440 us; speedup vs baseline: 1.3973x; 1.2126x over previous
//
#include <hip/hip_runtime.h>
#include <math.h>

#define MDIM 128
#define MY 10
#define GAMMA 0.8f
#define KITER 5

__device__ __forceinline__ float bf2f(unsigned short h) {
    return __uint_as_float(((unsigned int)h) << 16);
}
__device__ __forceinline__ unsigned short f2bf(float f) {
    unsigned int u = __float_as_uint(f);
    u += 0x7fffu + ((u >> 16) & 1u);  // round-to-nearest-even
    return (unsigned short)(u >> 16);
}

// ---------------------------------------------------------------- transpose
// X [128][n] -> Y0 fp32 [n][128] and Y0h bf16 [n][128]
__global__ void k_transpose(const float* __restrict__ X, float* __restrict__ Y0,
                            unsigned short* __restrict__ Y0h, int n) {
    __shared__ float tile[32][33];
    int r0 = blockIdx.x * 32;
    int f0 = blockIdx.y * 32;
    int tx = threadIdx.x, ty = threadIdx.y;  // 32 x 8
    #pragma unroll
    for (int i = 0; i < 32; i += 8) {
        tile[ty + i][tx] = X[(size_t)(f0 + ty + i) * n + (r0 + tx)];
    }
    __syncthreads();
    #pragma unroll
    for (int i = 0; i < 32; i += 8) {
        float v = tile[tx][ty + i];
        Y0[(size_t)(r0 + ty + i) * MDIM + (f0 + tx)] = v;
        Y0h[(size_t)(r0 + ty + i) * MDIM + (f0 + tx)] = f2bf(v);
    }
}

// ---------------------------------------------------------------- Gram matrix
__global__ void k_gram(const float* __restrict__ F, float* __restrict__ FF,
                       float* __restrict__ normAcc) {
    int i = blockIdx.x, j = threadIdx.x;
    float acc = 0.f;
    for (int k = 0; k < MDIM; ++k)
        acc = fmaf(F[k * MDIM + i], F[k * MDIM + j], acc);
    FF[i * MDIM + j] = acc;
    __shared__ float red[MDIM];
    red[j] = acc * acc;
    __syncthreads();
    for (int s = 64; s > 0; s >>= 1) {
        if (j < s) red[j] += red[j + s];
        __syncthreads();
    }
    if (j == 0) atomicAdd(normAcc, red[0]);
}

__global__ void k_gnorm(const float* __restrict__ FF, const float* __restrict__ normAcc,
                        float* __restrict__ G) {
    int idx = blockIdx.x * 256 + threadIdx.x;
    float s = GAMMA / (sqrtf(*normAcc) + 1e-6f);
    G[idx] = FF[idx] * s;
}

// ---------------------------------------------------------------- CSR build
__global__ void k_hist(const int* __restrict__ erow, int* __restrict__ cnt, int E) {
    int e = blockIdx.x * 256 + threadIdx.x;
    if (e < E) atomicAdd(&cnt[erow[e]], 1);
}

__global__ void k_scan1(const int* __restrict__ cnt, int* __restrict__ blockSums, int n) {
    int tid = threadIdx.x;  // 256
    int base = blockIdx.x * 1024 + tid * 4;
    int s = 0;
    if (base + 3 < n) {
        int4 v = *(const int4*)&cnt[base];
        s = v.x + v.y + v.z + v.w;
    } else {
        for (int i = 0; i < 4; ++i)
            if (base + i < n) s += cnt[base + i];
    }
    __shared__ int red[256];
    red[tid] = s;
    __syncthreads();
    for (int st = 128; st > 0; st >>= 1) {
        if (tid < st) red[tid] += red[tid + st];
        __syncthreads();
    }
    if (tid == 0) blockSums[blockIdx.x] = red[0];
}

__global__ void k_scan2(int* __restrict__ blockSums, int* __restrict__ row_off,
                        int nb, int n) {
    __shared__ int s[256];
    int tid = threadIdx.x;  // 256
    int v = (tid < nb) ? blockSums[tid] : 0;
    s[tid] = v;
    __syncthreads();
    for (int off = 1; off < 256; off <<= 1) {
        int t = (tid >= off) ? s[tid - off] : 0;
        __syncthreads();
        s[tid] += t;
        __syncthreads();
    }
    if (tid < nb) blockSums[tid] = s[tid] - v;
    if (tid == 0) row_off[n] = s[255];
}

__global__ void k_scan3(const int* __restrict__ cnt, const int* __restrict__ blockOff,
                        int* __restrict__ row_off, int n) {
    int tid = threadIdx.x;  // 256
    int base = blockIdx.x * 1024 + tid * 4;
    int v[4];
    #pragma unroll
    for (int i = 0; i < 4; ++i) v[i] = (base + i < n) ? cnt[base + i] : 0;
    int local = v[0] + v[1] + v[2] + v[3];
    __shared__ int s[256];
    s[tid] = local;
    __syncthreads();
    for (int off = 1; off < 256; off <<= 1) {
        int t = (tid >= off) ? s[tid - off] : 0;
        __syncthreads();
        s[tid] += t;
        __syncthreads();
    }
    int excl = s[tid] - local + blockOff[blockIdx.x];
    #pragma unroll
    for (int i = 0; i < 4; ++i) {
        if (base + i < n) { row_off[base + i] = excl; excl += v[i]; }
    }
}

__global__ void k_scatter(const int* __restrict__ erow, const int* __restrict__ ecol,
                          const float* __restrict__ eval_, int* __restrict__ cursor,
                          int* __restrict__ csr_col, float* __restrict__ csr_val, int E) {
    int e = blockIdx.x * 256 + threadIdx.x;
    if (e < E) {
        int r = erow[e];
        int pos = atomicAdd(&cursor[r], 1);
        csr_col[pos] = ecol[e];
        csr_val[pos] = eval_[e];
    }
}

// ---------------------------------------------------------------- SpMM: SY = S @ Yh
// Gathers bf16 rows (256 B): 32 lanes x ushort4(8B). Accumulate fp32. Unroll x4.
__global__ void __launch_bounds__(256) k_spmm(const unsigned short* __restrict__ Yh,
                                              const int* __restrict__ row_off,
                                              const int* __restrict__ csr_col,
                                              const float* __restrict__ csr_val,
                                              float* __restrict__ SY, int n) {
    int row = blockIdx.x * 8 + (threadIdx.x >> 5);
    int tx = threadIdx.x & 31;
    if (row >= n) return;
    int e0 = row_off[row], e1 = row_off[row + 1];
    float4 acc = make_float4(0.f, 0.f, 0.f, 0.f);
    int e = e0;
    for (; e + 4 <= e1; e += 4) {
        float v0 = csr_val[e + 0];
        float v1 = csr_val[e + 1];
        float v2 = csr_val[e + 2];
        float v3 = csr_val[e + 3];
        int c0 = csr_col[e + 0];
        int c1 = csr_col[e + 1];
        int c2 = csr_col[e + 2];
        int c3 = csr_col[e + 3];
        ushort4 h0 = *(const ushort4*)&Yh[(size_t)c0 * MDIM + tx * 4];
        ushort4 h1 = *(const ushort4*)&Yh[(size_t)c1 * MDIM + tx * 4];
        ushort4 h2 = *(const ushort4*)&Yh[(size_t)c2 * MDIM + tx * 4];
        ushort4 h3 = *(const ushort4*)&Yh[(size_t)c3 * MDIM + tx * 4];
        acc.x = fmaf(v0, bf2f(h0.x), acc.x);
        acc.y = fmaf(v0, bf2f(h0.y), acc.y);
        acc.z = fmaf(v0, bf2f(h0.z), acc.z);
        acc.w = fmaf(v0, bf2f(h0.w), acc.w);
        acc.x = fmaf(v1, bf2f(h1.x), acc.x);
        acc.y = fmaf(v1, bf2f(h1.y), acc.y);
        acc.z = fmaf(v1, bf2f(h1.z), acc.z);
        acc.w = fmaf(v1, bf2f(h1.w), acc.w);
        acc.x = fmaf(v2, bf2f(h2.x), acc.x);
        acc.y = fmaf(v2, bf2f(h2.y), acc.y);
        acc.z = fmaf(v2, bf2f(h2.z), acc.z);
        acc.w = fmaf(v2, bf2f(h2.w), acc.w);
        acc.x = fmaf(v3, bf2f(h3.x), acc.x);
        acc.y = fmaf(v3, bf2f(h3.y), acc.y);
        acc.z = fmaf(v3, bf2f(h3.z), acc.z);
        acc.w = fmaf(v3, bf2f(h3.w), acc.w);
    }
    for (; e < e1; ++e) {
        float v = csr_val[e];
        int c = csr_col[e];
        ushort4 h = *(const ushort4*)&Yh[(size_t)c * MDIM + tx * 4];
        acc.x = fmaf(v, bf2f(h.x), acc.x);
        acc.y = fmaf(v, bf2f(h.y), acc.y);
        acc.z = fmaf(v, bf2f(h.z), acc.z);
        acc.w = fmaf(v, bf2f(h.w), acc.w);
    }
    *(float4*)&SY[(size_t)row * MDIM + tx * 4] = acc;
}

// ---------------------------------------------------------------- dense update
// Yout = SY @ G + Y0 (fp32) and (optionally) bf16 copy Yhout for next spmm.
__global__ void __launch_bounds__(256) k_gemm(const float* __restrict__ SY,
                                              const float* __restrict__ G,
                                              const float* __restrict__ Y0,
                                              float* __restrict__ Yout,
                                              unsigned short* __restrict__ Yhout,
                                              int writeH, int n) {
    __shared__ float sG[MDIM * MDIM];
    int tid = threadIdx.x;
    #pragma unroll
    for (int i = 0; i < 16; ++i) {
        int idx = (i * 256 + tid) * 4;
        *(float4*)&sG[idx] = *(const float4*)&G[idx];
    }
    __syncthreads();
    int tx = tid & 31, ty = tid >> 5;
    size_t r0 = (size_t)blockIdx.x * 32 + ty * 4;
    int f0 = tx * 4;
    float4 acc[4];
    #pragma unroll
    for (int i = 0; i < 4; ++i) acc[i] = make_float4(0.f, 0.f, 0.f, 0.f);
    for (int j = 0; j < MDIM; j += 4) {
        float4 g0 = *(const float4*)&sG[(j + 0) * MDIM + f0];
        float4 g1 = *(const float4*)&sG[(j + 1) * MDIM + f0];
        float4 g2 = *(const float4*)&sG[(j + 2) * MDIM + f0];
        float4 g3 = *(const float4*)&sG[(j + 3) * MDIM + f0];
        #pragma unroll
        for (int i = 0; i < 4; ++i) {
            float4 sr = *(const float4*)&SY[(r0 + i) * MDIM + j];
            acc[i].x = fmaf(sr.x, g0.x, acc[i].x);
            acc[i].y = fmaf(sr.x, g0.y, acc[i].y);
            acc[i].z = fmaf(sr.x, g0.z, acc[i].z);
            acc[i].w = fmaf(sr.x, g0.w, acc[i].w);
            acc[i].x = fmaf(sr.y, g1.x, acc[i].x);
            acc[i].y = fmaf(sr.y, g1.y, acc[i].y);
            acc[i].z = fmaf(sr.y, g1.z, acc[i].z);
            acc[i].w = fmaf(sr.y, g1.w, acc[i].w);
            acc[i].x = fmaf(sr.z, g2.x, acc[i].x);
            acc[i].y = fmaf(sr.z, g2.y, acc[i].y);
            acc[i].z = fmaf(sr.z, g2.z, acc[i].z);
            acc[i].w = fmaf(sr.z, g2.w, acc[i].w);
            acc[i].x = fmaf(sr.w, g3.x, acc[i].x);
            acc[i].y = fmaf(sr.w, g3.y, acc[i].y);
            acc[i].z = fmaf(sr.w, g3.z, acc[i].z);
            acc[i].w = fmaf(sr.w, g3.w, acc[i].w);
        }
    }
    #pragma unroll
    for (int i = 0; i < 4; ++i) {
        float4 y0 = *(const float4*)&Y0[(r0 + i) * MDIM + f0];
        float4 o;
        o.x = acc[i].x + y0.x;
        o.y = acc[i].y + y0.y;
        o.z = acc[i].z + y0.z;
        o.w = acc[i].w + y0.w;
        *(float4*)&Yout[(r0 + i) * MDIM + f0] = o;
        if (writeH) {
            ushort4 h;
            h.x = f2bf(o.x);
            h.y = f2bf(o.y);
            h.z = f2bf(o.z);
            h.w = f2bf(o.w);
            *(ushort4*)&Yhout[(r0 + i) * MDIM + f0] = h;
        }
    }
}

// ---------------------------------------------------------------- BN stats
__global__ void k_bnstats(const float* __restrict__ Y, float* __restrict__ stats, int n) {
    int f = threadIdx.x;
    int chunk = (n + gridDim.x - 1) / gridDim.x;
    int rbeg = blockIdx.x * chunk;
    int rend = rbeg + chunk;
    if (rend > n) rend = n;
    float s = 0.f, sq = 0.f;
    for (int r = rbeg; r < rend; ++r) {
        float v = Y[(size_t)r * MDIM + f];
        s += v;
        sq = fmaf(v, v, sq);
    }
    atomicAdd(&stats[f], s);
    atomicAdd(&stats[MDIM + f], sq);
}

__global__ void k_finalize(const float* __restrict__ stats, const float* __restrict__ B,
                           const float* __restrict__ bnw, const float* __restrict__ bnb,
                           float* __restrict__ Bs, float* __restrict__ cvec, int n) {
    int f = threadIdx.x;
    float inv_n = 1.f / (float)n;
    float mu = stats[f] * inv_n;
    float var = stats[MDIM + f] * inv_n - mu * mu;
    float rs = rsqrtf(var + 1e-5f);
    float sw = rs * bnw[f];
    float cv = bnb[f] - mu * sw;
    __shared__ float red[MDIM];
    for (int o = 0; o < MY; ++o) {
        float b = B[o * MDIM + f];
        Bs[o * MDIM + f] = b * sw;
        red[f] = b * cv;
        __syncthreads();
        for (int s = 64; s > 0; s >>= 1) {
            if (f < s) red[f] += red[f + s];
            __syncthreads();
        }
        if (f == 0) cvec[o] = red[0];
        __syncthreads();
    }
}

// ---------------------------------------------------------------- projection
__global__ void __launch_bounds__(256) k_project(const float* __restrict__ Y,
                                                 const float* __restrict__ Bs,
                                                 const float* __restrict__ cvec,
                                                 float* __restrict__ out, int n) {
    __shared__ float yt[16 * 129];
    __shared__ float sB[MY * 129];
    __shared__ float sc[MY];
    int tid = threadIdx.x;
    size_t rbase = (size_t)blockIdx.x * 16;
    for (int idx = tid; idx < 16 * MDIM; idx += 256) {
        int r = idx >> 7, f = idx & 127;
        yt[r * 129 + f] = Y[(rbase + r) * MDIM + f];
    }
    for (int idx = tid; idx < MY * MDIM; idx += 256) {
        int o = idx >> 7, f = idx & 127;
        sB[o * 129 + f] = Bs[idx];
    }
    if (tid < MY) sc[tid] = cvec[tid];
    __syncthreads();
    if (tid < 16 * MY) {
        int r = tid / MY, o = tid % MY;
        float acc = sc[o];
        for (int f = 0; f < MDIM; ++f)
            acc = fmaf(yt[r * 129 + f], sB[o * 129 + f], acc);
        out[(rbase + r) * MY + o] = acc;
    }
}

// ---------------------------------------------------------------- launch
extern "C" void kernel_launch(void* const* d_in, const int* in_sizes, int n_in,
                              void* d_out, int out_size, void* d_ws, size_t ws_size,
                              hipStream_t stream) {
    const float* X    = (const float*)d_in[0];
    const float* F    = (const float*)d_in[1];
    const float* B    = (const float*)d_in[2];
    const float* bnw  = (const float*)d_in[3];
    const float* bnb  = (const float*)d_in[4];
    const float* ev   = (const float*)d_in[5];
    const int*   erow = (const int*)d_in[6];
    const int*   ecol = (const int*)d_in[7];
    float* out = (float*)d_out;
    const int n = in_sizes[0] / MDIM;  // 100000
    const int E = in_sizes[5];         // 1600000

    char* w = (char*)d_ws;
    size_t off = 0;
    auto carve = [&](size_t bytes) -> void* {
        void* p = w + off;
        off += (bytes + 255) & ~(size_t)255;
        return p;
    };
    float*          Y0    = (float*)carve((size_t)n * MDIM * 4);
    float*          Ycur  = (float*)carve((size_t)n * MDIM * 4);
    float*          SY    = (float*)carve((size_t)n * MDIM * 4);
    unsigned short* Yh    = (unsigned short*)carve((size_t)n * MDIM * 2);  // bf16 state
    float* FF        = (float*)carve(MDIM * MDIM * 4);
    float* G         = (float*)carve(MDIM * MDIM * 4);
    float* csr_val   = (float*)carve((size_t)E * 4);
    int*   csr_col   = (int*)carve((size_t)E * 4);
    int*   row_off   = (int*)carve((size_t)(n + 1) * 4);
    int*   cursor    = (int*)carve((size_t)n * 4);
    int*   cnt       = (int*)carve((size_t)n * 4);
    int*   blockSums = (int*)carve(1024 * 4);
    float* normAcc   = (float*)carve(4);
    float* stats     = (float*)carve(2 * MDIM * 4);
    float* Bs        = (float*)carve(MY * MDIM * 4);
    float* cvec      = (float*)carve(MY * 4);
    (void)ws_size;

    hipMemsetAsync(cnt, 0, (size_t)n * 4, stream);
    hipMemsetAsync(normAcc, 0, 4, stream);
    hipMemsetAsync(stats, 0, 2 * MDIM * 4, stream);

    k_transpose<<<dim3(n / 32, MDIM / 32), dim3(32, 8), 0, stream>>>(X, Y0, Yh, n);
    k_gram<<<MDIM, MDIM, 0, stream>>>(F, FF, normAcc);
    k_gnorm<<<MDIM * MDIM / 256, 256, 0, stream>>>(FF, normAcc, G);

    const int nb = (n + 1023) / 1024;
    k_hist<<<(E + 255) / 256, 256, 0, stream>>>(erow, cnt, E);
    k_scan1<<<nb, 256, 0, stream>>>(cnt, blockSums, n);
    k_scan2<<<1, 256, 0, stream>>>(blockSums, row_off, nb, n);
    k_scan3<<<nb, 256, 0, stream>>>(cnt, blockSums, row_off, n);
    hipMemcpyAsync(cursor, row_off, (size_t)n * 4, hipMemcpyDeviceToDevice, stream);
    k_scatter<<<(E + 255) / 256, 256, 0, stream>>>(erow, ecol, ev, cursor, csr_col, csr_val, E);

    for (int k = 0; k < KITER; ++k) {
        k_spmm<<<(n + 7) / 8, 256, 0, stream>>>(Yh, row_off, csr_col, csr_val, SY, n);
        int writeH = (k < KITER - 1) ? 1 : 0;
        k_gemm<<<n / 32, 256, 0, stream>>>(SY, G, Y0, Ycur, Yh, writeH, n);
    }

    k_bnstats<<<256, MDIM, 0, stream>>>(Ycur, stats, n);
    k_finalize<<<1, MDIM, 0, stream>>>(stats, B, bnw, bnb, Bs, cvec, n);
    k_project<<<n / 16, 256, 0, stream>>>(Ycur, Bs, cvec, out, n);
}